// Round 14
// baseline (420.460 us; speedup 1.0000x reference)
//
#include <hip/hip_runtime.h>
#include <cstdint>
#include <cstddef>

#define M_ROWS 65536
#define N_COLS 1024
#define K_DIM  1024

typedef _Float16 f16x8 __attribute__((ext_vector_type(8)));
typedef float f32x4 __attribute__((ext_vector_type(4)));

// ---------------- prep: scale/bias ----------------
__global__ __launch_bounds__(256) void prep_scale_bias(
    const float* __restrict__ gamma, const float* __restrict__ beta,
    const float* __restrict__ mean, const float* __restrict__ var,
    float* __restrict__ bias, float* __restrict__ scale)
{
  int i = blockIdx.x * 256 + threadIdx.x;
  if (i < N_COLS) {
    float s = gamma[i] * rsqrtf(var[i] + 1e-3f);
    scale[i] = s;
    bias[i] = beta[i] - mean[i] * s;
  }
}

// ---------------- prep: W -> Wt (transposed, scaled, f16) ----------------
__global__ __launch_bounds__(256) void prep_wt(
    const float* __restrict__ W, const float* __restrict__ scale,
    _Float16* __restrict__ Wt)
{
  __shared__ float tile[64][68];
  int k0 = blockIdx.x * 64, n0 = blockIdx.y * 64;
  int t = threadIdx.x;
  int kr = t >> 2, q = t & 3;
  #pragma unroll
  for (int j = 0; j < 4; ++j) {
    float4 v = *(const float4*)(W + (size_t)(k0 + kr) * N_COLS + n0 + q * 16 + j * 4);
    *(float4*)(&tile[kr][q * 16 + j * 4]) = v;
  }
  __syncthreads();
  int nr = t >> 2;
  float sn = scale[n0 + nr];
  __align__(16) _Float16 h[16];
  #pragma unroll
  for (int j = 0; j < 16; ++j)
    h[j] = (_Float16)(tile[q * 16 + j][nr] * sn);
  uint4* dst = (uint4*)(Wt + (size_t)(n0 + nr) * K_DIM + k0 + q * 16);
  dst[0] = *(uint4*)(&h[0]);
  dst[1] = *(uint4*)(&h[8]);
}

// ---------------- prep: A (fp32) -> Af (f16), grid-stride, vectorized ----------------
__global__ __launch_bounds__(256) void conv_a_f16(
    const float* __restrict__ A, _Float16* __restrict__ Af)
{
  const size_t total8 = (size_t)M_ROWS * K_DIM / 8;
  size_t i = (size_t)blockIdx.x * 256 + threadIdx.x;
  const size_t stride = (size_t)gridDim.x * 256;
  for (; i < total8; i += stride) {
    float4 a = *(const float4*)(A + i * 8);
    float4 b = *(const float4*)(A + i * 8 + 4);
    union { _Float16 h[8]; uint4 u; } p;
    p.h[0] = (_Float16)a.x; p.h[1] = (_Float16)a.y;
    p.h[2] = (_Float16)a.z; p.h[3] = (_Float16)a.w;
    p.h[4] = (_Float16)b.x; p.h[5] = (_Float16)b.y;
    p.h[6] = (_Float16)b.z; p.h[7] = (_Float16)b.w;
    *(uint4*)(Af + i * 8) = p.u;
  }
}

// ---------------- 256x256 8-wave GEMM: R11 geometry + R10 counted ledger +
// LDS-transpose vectorized epilogue ----------------
// 512 threads = 8 waves (2M x 4N); per wave 128x64 output, acc[8][4] in AGPRs.
// LDS 128 KB dbuf. Ledger: prologue stages t0,t1 (8 loads/thread each pair);
// top of body t: vmcnt(8) -> stage(t) done, stage(t+1) IN FLIGHT across barrier;
// after body lgkmcnt(0)+barrier: stage(t+2) into freed buffer. Never vmcnt(0)
// in-loop until the tail. Epilogue: acc -> f16 LDS tile (XOR-swizzled rows),
// then per-row coalesced streams (priors float4, zh uint2).
template<int F16OUT>
__global__ __launch_bounds__(512, 2) void gemm_256v(
    const _Float16* __restrict__ Af, const _Float16* __restrict__ Wt,
    const float* __restrict__ bias, const float* __restrict__ priors,
    void* __restrict__ zout)
{
  __shared__ char smem[131072];   // buf d: A @ d*65536 (32KB), B @ d*65536+32768 (32KB)
  const int tid = threadIdx.x;
  const int lane = tid & 63, wid = tid >> 6;
  const int wm = wid >> 2, wn = wid & 3;
  const int li = lane & 15, g = lane >> 4;

  // bijective XCD swizzle (nwg=1024, 1024%8==0)
  int orig = blockIdx.x;
  int wgid = (orig & 7) * 128 + (orig >> 3);
  int mb = wgid >> 2, nb = wgid & 3;
  const int m0 = mb * 256, n0 = nb * 256;

  f32x4 acc[8][4];
  #pragma unroll
  for (int i = 0; i < 8; ++i)
    #pragma unroll
    for (int j = 0; j < 4; ++j) acc[i][j] = (f32x4){0.f, 0.f, 0.f, 0.f};

  // wave-split staging shares (proven R11)
  const int arow0 = wm * 128 + wn * 32;                          // my 32 A-rows (local)
  const int bcol0 = (wn >> 1) * 128 + (wm * 2 + (wn & 1)) * 32;  // my 32 B-cols (local)

  auto stageA = [&](int kt, int buf) {
    #pragma unroll
    for (int j = 0; j < 4; ++j) {
      int ch = j * 64 + lane;            // 256 chunks: 32 rows x 8
      int rloc = ch >> 3, c = ch & 7;
      int row = arow0 + rloc;
      const char* src = (const char*)Af + ((size_t)(m0 + row) * K_DIM + kt * 64) * 2
                        + ((c * 16) ^ ((row & 7) << 4));
      __builtin_amdgcn_global_load_lds(
          (const __attribute__((address_space(1))) unsigned int*)src,
          (__attribute__((address_space(3))) unsigned int*)(&smem[buf * 65536 + arow0 * 128 + ch * 16]),
          16, 0, 0);
    }
  };
  auto stageB = [&](int kt, int buf) {
    #pragma unroll
    for (int j = 0; j < 4; ++j) {
      int ch = j * 64 + lane;
      int rloc = ch >> 3, c = ch & 7;
      int col = bcol0 + rloc;
      const char* src = (const char*)Wt + ((size_t)(n0 + col) * K_DIM + kt * 64) * 2
                        + ((c * 16) ^ ((col & 7) << 4));
      __builtin_amdgcn_global_load_lds(
          (const __attribute__((address_space(1))) unsigned int*)src,
          (__attribute__((address_space(3))) unsigned int*)(&smem[buf * 65536 + 32768 + bcol0 * 128 + ch * 16]),
          16, 0, 0);
    }
  };

  const int aswz = (li & 7) << 4;

  // prologue: stage t0 and t1 (16 loads/thread outstanding)
  stageA(0, 0); stageB(0, 0);
  stageA(1, 1); stageB(1, 1);

  for (int t = 0; t < 16; ++t) {
    // counted wait: stage(t) complete (oldest 8); stage(t+1)'s 8 stay in flight
    if (t < 15) asm volatile("s_waitcnt vmcnt(8)" ::: "memory");
    else        asm volatile("s_waitcnt vmcnt(0)" ::: "memory");
    __builtin_amdgcn_s_barrier();
    asm volatile("" ::: "memory");
    __builtin_amdgcn_sched_barrier(0);

    const int cur = t & 1;
    const int abase = cur * 65536, bbase = cur * 65536 + 32768;

    #pragma unroll
    for (int q = 0; q < 4; ++q) {
      const int qr = q >> 1, qc = q & 1;
      f16x8 af[4][2], bf[2][2];
      #pragma unroll
      for (int kc = 0; kc < 2; ++kc) {
        const int koff = (kc * 64 + g * 16) ^ aswz;
        #pragma unroll
        for (int fr = 0; fr < 4; ++fr) {
          int row = wm * 128 + qr * 64 + fr * 16 + li;
          af[fr][kc] = *(const f16x8*)(&smem[abase + row * 128 + koff]);
        }
        #pragma unroll
        for (int fc = 0; fc < 2; ++fc) {
          int col = wn * 64 + qc * 32 + fc * 16 + li;
          bf[fc][kc] = *(const f16x8*)(&smem[bbase + col * 128 + koff]);
        }
      }
      __builtin_amdgcn_s_setprio(1);
      #pragma unroll
      for (int kc = 0; kc < 2; ++kc)
        #pragma unroll
        for (int fr = 0; fr < 4; ++fr)
          #pragma unroll
          for (int fc = 0; fc < 2; ++fc)
            acc[qr * 4 + fr][qc * 2 + fc] = __builtin_amdgcn_mfma_f32_16x16x32_f16(
                af[fr][kc], bf[fc][kc], acc[qr * 4 + fr][qc * 2 + fc], 0, 0, 0);
      __builtin_amdgcn_s_setprio(0);
    }

    asm volatile("s_waitcnt lgkmcnt(0)" ::: "memory"); // my LDS reads retired
    __builtin_amdgcn_s_barrier();                      // buf[cur] free for restage
    asm volatile("" ::: "memory");
    __builtin_amdgcn_sched_barrier(0);
    // restage just-freed buffer with K-tile t+2 (kept in flight across next wait)
    if (t < 14) { stageA(t + 2, cur); stageB(t + 2, cur); }
  }

  // ---- epilogue: acc -> f16 LDS [256 rows][512B], XOR-swizzled; then coalesced streams ----
  // (loop ended with lgkmcnt(0)+barrier: all waves done with LDS -> safe to overwrite)
  #pragma unroll
  for (int i = 0; i < 8; ++i) {
    #pragma unroll
    for (int r = 0; r < 4; ++r) {
      int lrow = wm * 128 + i * 16 + g * 4 + r;
      int sw = (lrow & 7) << 4;
      #pragma unroll
      for (int j = 0; j < 4; ++j) {
        int cb = (wn * 64 + j * 16 + li) * 2;
        *(_Float16*)(&smem[lrow * 512 + (cb ^ sw)]) = (_Float16)acc[i][j][r];
      }
    }
  }
  __builtin_amdgcn_s_barrier();

  // readout: wave w owns rows [w*32, w*32+32); per row, 64 lanes cover 256 cols (4 each)
  {
    float4 b4 = *(const float4*)(bias + n0 + lane * 4);
    #pragma unroll 4
    for (int rr = 0; rr < 32; ++rr) {
      int lrow = wid * 32 + rr;
      int sw = (lrow & 7) << 4;
      union { uint2 u; _Float16 h[4]; } hv;
      hv.u = *(const uint2*)(&smem[lrow * 512 + ((lane * 8) ^ sw)]);
      size_t grow = (size_t)(m0 + lrow);
      float4 p4 = *(const float4*)(priors + grow * N_COLS + n0 + lane * 4);
      float z0 = ((float)hv.h[0] + b4.x) * p4.x;
      float z1 = ((float)hv.h[1] + b4.y) * p4.y;
      float z2 = ((float)hv.h[2] + b4.z) * p4.z;
      float z3 = ((float)hv.h[3] + b4.w) * p4.w;
      if (F16OUT) {
        union { _Float16 h[4]; uint2 u; } o;
        o.h[0] = (_Float16)z0; o.h[1] = (_Float16)z1;
        o.h[2] = (_Float16)z2; o.h[3] = (_Float16)z3;
        *(uint2*)((_Float16*)zout + grow * N_COLS + n0 + lane * 4) = o.u;
      } else {
        float4 o4 = {z0, z1, z2, z3};
        *(float4*)((float*)zout + grow * N_COLS + n0 + lane * 4) = o4;
      }
    }
  }
}

// ---------------- sparsemax from f16 z -> f32 out, one wave per row ----------------
__global__ __launch_bounds__(256) void sparsemax_rows_h(
    const _Float16* __restrict__ zh, float* __restrict__ outp)
{
  const int lane = threadIdx.x & 63, wid = threadIdx.x >> 6;
  const size_t row = (size_t)blockIdx.x * 4 + wid;
  const _Float16* p = zh + row * N_COLS + lane * 16;

  f16x8 h0 = *(const f16x8*)(p);
  f16x8 h1 = *(const f16x8*)(p + 8);
  float v[16];
  #pragma unroll
  for (int j = 0; j < 8; ++j) { v[j] = (float)h0[j]; v[8 + j] = (float)h1[j]; }

  float mx = v[0];
  #pragma unroll
  for (int j = 1; j < 16; ++j) mx = fmaxf(mx, v[j]);
  #pragma unroll
  for (int m = 1; m <= 32; m <<= 1) mx = fmaxf(mx, __shfl_xor(mx, m, 64));

  float lo = mx - 1.0f, hi = mx;
  for (int it = 0; it < 12; ++it) {
    float tau = 0.5f * (lo + hi);
    float s = 0.f;
    #pragma unroll
    for (int j = 0; j < 16; ++j) s += fmaxf(v[j] - tau, 0.f);
    #pragma unroll
    for (int m = 1; m <= 32; m <<= 1) s += __shfl_xor(s, m, 64);
    if (s >= 1.f) lo = tau; else hi = tau;
  }
  float tau = lo;
  #pragma unroll
  for (int it = 0; it < 2; ++it) {
    float s = 0.f, k = 0.f;
    #pragma unroll
    for (int j = 0; j < 16; ++j) {
      bool g = v[j] > tau;
      s += g ? v[j] : 0.f;
      k += g ? 1.f : 0.f;
    }
    #pragma unroll
    for (int m = 1; m <= 32; m <<= 1) { s += __shfl_xor(s, m, 64); k += __shfl_xor(k, m, 64); }
    tau = (s - 1.f) / k;   // k >= 1 (row max stays in support)
  }

  float* o = outp + row * N_COLS + lane * 16;
  #pragma unroll
  for (int j = 0; j < 4; ++j) {
    float4 t;
    t.x = fmaxf(v[j * 4 + 0] - tau, 0.f);
    t.y = fmaxf(v[j * 4 + 1] - tau, 0.f);
    t.z = fmaxf(v[j * 4 + 2] - tau, 0.f);
    t.w = fmaxf(v[j * 4 + 3] - tau, 0.f);
    *(float4*)(o + j * 4) = t;
  }
}

// ---------------- sparsemax in place on f32 z (mid path) ----------------
__global__ __launch_bounds__(256) void sparsemax_rows(float* __restrict__ z)
{
  const int lane = threadIdx.x & 63, wid = threadIdx.x >> 6;
  const size_t row = (size_t)blockIdx.x * 4 + wid;
  float* p = z + row * N_COLS;
  float v[16];
  #pragma unroll
  for (int j = 0; j < 4; ++j) {
    float4 t = *(const float4*)(p + j * 256 + lane * 4);
    v[j * 4 + 0] = t.x; v[j * 4 + 1] = t.y; v[j * 4 + 2] = t.z; v[j * 4 + 3] = t.w;
  }
  float mx = v[0];
  #pragma unroll
  for (int j = 1; j < 16; ++j) mx = fmaxf(mx, v[j]);
  #pragma unroll
  for (int m = 1; m <= 32; m <<= 1) mx = fmaxf(mx, __shfl_xor(mx, m, 64));
  float lo = mx - 1.0f, hi = mx;
  for (int it = 0; it < 12; ++it) {
    float tau = 0.5f * (lo + hi);
    float s = 0.f;
    #pragma unroll
    for (int j = 0; j < 16; ++j) s += fmaxf(v[j] - tau, 0.f);
    #pragma unroll
    for (int m = 1; m <= 32; m <<= 1) s += __shfl_xor(s, m, 64);
    if (s >= 1.f) lo = tau; else hi = tau;
  }
  float tau = lo;
  #pragma unroll
  for (int it = 0; it < 2; ++it) {
    float s = 0.f, k = 0.f;
    #pragma unroll
    for (int j = 0; j < 16; ++j) {
      bool g = v[j] > tau;
      s += g ? v[j] : 0.f;
      k += g ? 1.f : 0.f;
    }
    #pragma unroll
    for (int m = 1; m <= 32; m <<= 1) { s += __shfl_xor(s, m, 64); k += __shfl_xor(k, m, 64); }
    tau = (s - 1.f) / k;
  }
  #pragma unroll
  for (int j = 0; j < 4; ++j) {
    float4 t;
    t.x = fmaxf(v[j * 4 + 0] - tau, 0.f);
    t.y = fmaxf(v[j * 4 + 1] - tau, 0.f);
    t.z = fmaxf(v[j * 4 + 2] - tau, 0.f);
    t.w = fmaxf(v[j * 4 + 3] - tau, 0.f);
    *(float4*)(p + j * 256 + lane * 4) = t;
  }
}

// ---------------- FALLBACK GEMM (tiny ws): A reg-staged fp32->f16, dbuf ----------------
__global__ __launch_bounds__(256, 2) void gemm_f16(
    const float* __restrict__ A, const _Float16* __restrict__ Wt,
    const float* __restrict__ bias, const float* __restrict__ priors,
    float* __restrict__ out)
{
  __shared__ char smem[65536];
  const int tid = threadIdx.x;
  const int lane = tid & 63, wid = tid >> 6;
  const int wm = wid >> 1, wnn = wid & 1;
  int orig = blockIdx.x;
  int wgid = (orig & 7) * 512 + (orig >> 3);
  int mb = wgid >> 3, nb = wgid & 7;
  const int m0 = mb * 128, n0 = nb * 128;
  f32x4 acc[4][4];
  #pragma unroll
  for (int i = 0; i < 4; ++i)
    #pragma unroll
    for (int j = 0; j < 4; ++j) acc[i][j] = (f32x4){0.f, 0.f, 0.f, 0.f};
  float4 areg[8];
  auto loadA = [&](int kt) {
    #pragma unroll
    for (int j = 0; j < 8; ++j) {
      int f = j * 256 + tid;
      int ml = f >> 4, k4 = (f & 15) << 2;
      areg[j] = *(const float4*)(A + (size_t)(m0 + ml) * K_DIM + kt * 64 + k4);
    }
  };
  auto storeA = [&](int buf) {
    int base = buf * 16384;
    #pragma unroll
    for (int j = 0; j < 8; ++j) {
      int f = j * 256 + tid;
      int ml = f >> 4, k4 = (f & 15) << 2;
      int off = ml * 128 + ((k4 * 2) ^ ((ml & 7) << 4));
      union { _Float16 h[4]; uint2 u; } p;
      p.h[0] = (_Float16)areg[j].x; p.h[1] = (_Float16)areg[j].y;
      p.h[2] = (_Float16)areg[j].z; p.h[3] = (_Float16)areg[j].w;
      *(uint2*)(&smem[base + off]) = p.u;
    }
  };
  auto issueB = [&](int kt, int buf) {
    int base = 32768 + buf * 16384;
    #pragma unroll
    for (int t4 = 0; t4 < 4; ++t4) {
      int ch = t4 * 256 + tid;
      int nl = ch >> 3, c = ch & 7;
      const char* src = (const char*)Wt + ((size_t)(n0 + nl) * K_DIM + kt * 64) * 2
          + ((c * 16) ^ ((nl & 7) << 4));
      __builtin_amdgcn_global_load_lds(
          (const __attribute__((address_space(1))) unsigned int*)src,
          (__attribute__((address_space(3))) unsigned int*)(&smem[base + ch * 16]),
          16, 0, 0);
    }
  };
  loadA(0); issueB(0, 0); storeA(0);
  __syncthreads();
  for (int kt = 0; kt < 16; ++kt) {
    int curb = kt & 1, nxt = curb ^ 1;
    if (kt < 15) { loadA(kt + 1); issueB(kt + 1, nxt); }
    int ab = curb * 16384, bb = 32768 + curb * 16384;
    #pragma unroll
    for (int kc = 0; kc < 2; ++kc) {
      int k2 = (kc * 32 + ((lane >> 4) * 8)) * 2;
      f16x8 af[4], bfr[4];
      #pragma unroll
      for (int fm = 0; fm < 4; ++fm) {
        int rl2 = wm * 64 + fm * 16 + (lane & 15);
        af[fm] = *(const f16x8*)(&smem[ab + rl2 * 128 + (k2 ^ ((rl2 & 7) << 4))]);
      }
      #pragma unroll
      for (int fn = 0; fn < 4; ++fn) {
        int nl = wnn * 64 + fn * 16 + (lane & 15);
        bfr[fn] = *(const f16x8*)(&smem[bb + nl * 128 + (k2 ^ ((nl & 7) << 4))]);
      }
      #pragma unroll
      for (int fm = 0; fm < 4; ++fm)
        #pragma unroll
        for (int fn = 0; fn < 4; ++fn)
          acc[fm][fn] = __builtin_amdgcn_mfma_f32_16x16x32_f16(af[fm], bfr[fn], acc[fm][fn], 0, 0, 0);
    }
    if (kt < 15) storeA(nxt);
    __syncthreads();
  }
  #pragma unroll
  for (int fn = 0; fn < 4; ++fn) {
    int col = n0 + wnn * 64 + fn * 16 + (lane & 15);
    float bvv = bias[col];
    #pragma unroll
    for (int fm = 0; fm < 4; ++fm) {
      int row0 = m0 + wm * 64 + fm * 16 + ((lane >> 4) << 2);
      #pragma unroll
      for (int r = 0; r < 4; ++r) {
        size_t idx = (size_t)(row0 + r) * N_COLS + col;
        out[idx] = (acc[fm][fn][r] + bvv) * priors[idx];
      }
    }
  }
}

// ---------------- launch ----------------
extern "C" void kernel_launch(void* const* d_in, const int* in_sizes, int n_in,
                              void* d_out, int out_size, void* d_ws, size_t ws_size,
                              hipStream_t stream) {
  const float* inputs = (const float*)d_in[0];
  const float* priors = (const float*)d_in[1];
  const float* W      = (const float*)d_in[2];
  const float* gamma  = (const float*)d_in[3];
  const float* beta   = (const float*)d_in[4];
  const float* mean   = (const float*)d_in[5];
  const float* var    = (const float*)d_in[6];
  float* out = (float*)d_out;

  char* ws = (char*)d_ws;
  float* bias  = (float*)ws;                 // 4 KB
  float* scale = (float*)(ws + 4096);        // 4 KB
  _Float16* Wt = (_Float16*)(ws + 8192);     // 2 MB, [N][K] transposed+scaled
  const size_t AF_OFF = 8192 + (size_t)N_COLS * K_DIM * 2;          // 2105344
  _Float16* Af = (_Float16*)(ws + AF_OFF);   // 134 MB, [M][K] f16
  const size_t ZH_OFF = AF_OFF + (size_t)M_ROWS * K_DIM * 2;        // 136323072
  _Float16* zh = (_Float16*)(ws + ZH_OFF);   // 134 MB, [M][N] f16 z
  const size_t need  = ZH_OFF;
  const size_t need2 = ZH_OFF + (size_t)M_ROWS * N_COLS * 2;

  prep_scale_bias<<<4, 256, 0, stream>>>(gamma, beta, mean, var, bias, scale);
  prep_wt<<<dim3(16, 16), 256, 0, stream>>>(W, scale, Wt);

  if (ws_size >= need2) {
    conv_a_f16<<<2048, 256, 0, stream>>>(inputs, Af);
    gemm_256v<1><<<1024, 512, 0, stream>>>(Af, Wt, bias, priors, zh);
    sparsemax_rows_h<<<16384, 256, 0, stream>>>(zh, out);
  } else if (ws_size >= need) {
    conv_a_f16<<<2048, 256, 0, stream>>>(inputs, Af);
    gemm_256v<0><<<1024, 512, 0, stream>>>(Af, Wt, bias, priors, out);
    sparsemax_rows<<<16384, 256, 0, stream>>>(out);
  } else {
    gemm_f16<<<4096, 256, 0, stream>>>(inputs, Wt, bias, priors, out);
    sparsemax_rows<<<16384, 256, 0, stream>>>(out);
  }
}

// Round 15
// 408.270 us; speedup vs baseline: 1.0299x; 1.0299x over previous
//
#include <hip/hip_runtime.h>
#include <cstdint>
#include <cstddef>

#define M_ROWS 65536
#define N_COLS 1024
#define K_DIM  1024

typedef _Float16 f16x8 __attribute__((ext_vector_type(8)));
typedef float f32x4 __attribute__((ext_vector_type(4)));

// ---------------- prep: scale/bias ----------------
__global__ __launch_bounds__(256) void prep_scale_bias(
    const float* __restrict__ gamma, const float* __restrict__ beta,
    const float* __restrict__ mean, const float* __restrict__ var,
    float* __restrict__ bias, float* __restrict__ scale)
{
  int i = blockIdx.x * 256 + threadIdx.x;
  if (i < N_COLS) {
    float s = gamma[i] * rsqrtf(var[i] + 1e-3f);
    scale[i] = s;
    bias[i] = beta[i] - mean[i] * s;
  }
}

// ---------------- prep: W -> Wt (transposed, scaled, f16) ----------------
__global__ __launch_bounds__(256) void prep_wt(
    const float* __restrict__ W, const float* __restrict__ scale,
    _Float16* __restrict__ Wt)
{
  __shared__ float tile[64][68];
  int k0 = blockIdx.x * 64, n0 = blockIdx.y * 64;
  int t = threadIdx.x;
  int kr = t >> 2, q = t & 3;
  #pragma unroll
  for (int j = 0; j < 4; ++j) {
    float4 v = *(const float4*)(W + (size_t)(k0 + kr) * N_COLS + n0 + q * 16 + j * 4);
    *(float4*)(&tile[kr][q * 16 + j * 4]) = v;
  }
  __syncthreads();
  int nr = t >> 2;
  float sn = scale[n0 + nr];
  __align__(16) _Float16 h[16];
  #pragma unroll
  for (int j = 0; j < 16; ++j)
    h[j] = (_Float16)(tile[q * 16 + j][nr] * sn);
  uint4* dst = (uint4*)(Wt + (size_t)(n0 + nr) * K_DIM + k0 + q * 16);
  dst[0] = *(uint4*)(&h[0]);
  dst[1] = *(uint4*)(&h[8]);
}

// ---------------- prep: A (fp32) -> Af (f16), grid-stride, vectorized ----------------
__global__ __launch_bounds__(256) void conv_a_f16(
    const float* __restrict__ A, _Float16* __restrict__ Af)
{
  const size_t total8 = (size_t)M_ROWS * K_DIM / 8;
  size_t i = (size_t)blockIdx.x * 256 + threadIdx.x;
  const size_t stride = (size_t)gridDim.x * 256;
  for (; i < total8; i += stride) {
    float4 a = *(const float4*)(A + i * 8);
    float4 b = *(const float4*)(A + i * 8 + 4);
    union { _Float16 h[8]; uint4 u; } p;
    p.h[0] = (_Float16)a.x; p.h[1] = (_Float16)a.y;
    p.h[2] = (_Float16)a.z; p.h[3] = (_Float16)a.w;
    p.h[4] = (_Float16)b.x; p.h[5] = (_Float16)b.y;
    p.h[6] = (_Float16)b.z; p.h[7] = (_Float16)b.w;
    *(uint4*)(Af + i * 8) = p.u;
  }
}

// ---------------- 256x256 8-wave GEMM (R11 config — session best) ----------------
// 512 threads = 8 waves (2M x 4N); per wave 128x64 output, acc[8][4] in AGPRs.
// LDS 128 KB dbuf: A 32KB + B 32KB per buffer, m97-proven 128B rows + XOR swizzle.
// Wave-split staging: each wave stages its own 32 A-rows + 32 B-cols (8 loads) for
// ktile t+1, issued in quadrants 0-1 of body t -> >=half-body latency cover; the
// top-of-body vmcnt(0) waits only on loads issued ~3 quadrants earlier (nearly free).
template<int F16OUT>
__global__ __launch_bounds__(512, 2) void gemm_256(
    const _Float16* __restrict__ Af, const _Float16* __restrict__ Wt,
    const float* __restrict__ bias, const float* __restrict__ priors,
    void* __restrict__ zout)
{
  __shared__ char smem[131072];   // buf b: A @ b*65536, B @ b*65536+32768
  const int tid = threadIdx.x;
  const int lane = tid & 63, wid = tid >> 6;
  const int wm = wid >> 2, wn = wid & 3;
  const int li = lane & 15, g = lane >> 4;

  // bijective XCD swizzle (nwg=1024, 1024%8==0)
  int orig = blockIdx.x;
  int wgid = (orig & 7) * 128 + (orig >> 3);
  int mb = wgid >> 2, nb = wgid & 3;
  const int m0 = mb * 256, n0 = nb * 256;

  f32x4 acc[8][4];
  #pragma unroll
  for (int i = 0; i < 8; ++i)
    #pragma unroll
    for (int j = 0; j < 4; ++j) acc[i][j] = (f32x4){0.f, 0.f, 0.f, 0.f};

  // wave-split staging shares
  const int arow0 = wm * 128 + wn * 32;                          // my 32 A-rows (local)
  const int bcol0 = (wn >> 1) * 128 + (wm * 2 + (wn & 1)) * 32;  // my 32 B-cols (local)

  auto stageA = [&](int kt, int buf) {
    #pragma unroll
    for (int j = 0; j < 4; ++j) {
      int ch = j * 64 + lane;            // 256 chunks: 32 rows x 8
      int rloc = ch >> 3, c = ch & 7;
      int row = arow0 + rloc;
      const char* src = (const char*)Af + ((size_t)(m0 + row) * K_DIM + kt * 64) * 2
                        + ((c * 16) ^ ((row & 7) << 4));
      __builtin_amdgcn_global_load_lds(
          (const __attribute__((address_space(1))) unsigned int*)src,
          (__attribute__((address_space(3))) unsigned int*)(&smem[buf * 65536 + arow0 * 128 + ch * 16]),
          16, 0, 0);
    }
  };
  auto stageB = [&](int kt, int buf) {
    #pragma unroll
    for (int j = 0; j < 4; ++j) {
      int ch = j * 64 + lane;
      int rloc = ch >> 3, c = ch & 7;
      int col = bcol0 + rloc;
      const char* src = (const char*)Wt + ((size_t)(n0 + col) * K_DIM + kt * 64) * 2
                        + ((c * 16) ^ ((col & 7) << 4));
      __builtin_amdgcn_global_load_lds(
          (const __attribute__((address_space(1))) unsigned int*)src,
          (__attribute__((address_space(3))) unsigned int*)(&smem[buf * 65536 + 32768 + bcol0 * 128 + ch * 16]),
          16, 0, 0);
    }
  };

  const int aswz = (li & 7) << 4;

  // prologue: stage ktile 0 into buf 0
  stageA(0, 0);
  stageB(0, 0);

  for (int t = 0; t < 16; ++t) {
    asm volatile("s_waitcnt vmcnt(0)" ::: "memory");   // my stage loads for ktile t landed
    __builtin_amdgcn_s_barrier();                      // everyone's landed
    asm volatile("" ::: "memory");
    __builtin_amdgcn_sched_barrier(0);

    const int cur = t & 1;
    const int abase = cur * 65536, bbase = cur * 65536 + 32768;
    const int ktn = (t + 1 < 16) ? t + 1 : 15;         // clamped (redundant tail stage harmless)

    #pragma unroll
    for (int q = 0; q < 4; ++q) {
      if (q == 0) stageA(ktn, cur ^ 1);                // early issue -> latency cover
      if (q == 1) stageB(ktn, cur ^ 1);
      const int qr = q >> 1, qc = q & 1;
      f16x8 af[4][2], bf[2][2];
      #pragma unroll
      for (int kc = 0; kc < 2; ++kc) {
        const int koff = (kc * 64 + g * 16) ^ aswz;
        #pragma unroll
        for (int fr = 0; fr < 4; ++fr) {
          int row = wm * 128 + qr * 64 + fr * 16 + li;
          af[fr][kc] = *(const f16x8*)(&smem[abase + row * 128 + koff]);
        }
        #pragma unroll
        for (int fc = 0; fc < 2; ++fc) {
          int col = wn * 64 + qc * 32 + fc * 16 + li;
          bf[fc][kc] = *(const f16x8*)(&smem[bbase + col * 128 + koff]);
        }
      }
      __builtin_amdgcn_s_setprio(1);
      #pragma unroll
      for (int kc = 0; kc < 2; ++kc)
        #pragma unroll
        for (int fr = 0; fr < 4; ++fr)
          #pragma unroll
          for (int fc = 0; fc < 2; ++fc)
            acc[qr * 4 + fr][qc * 2 + fc] = __builtin_amdgcn_mfma_f32_16x16x32_f16(
                af[fr][kc], bf[fc][kc], acc[qr * 4 + fr][qc * 2 + fc], 0, 0, 0);
      __builtin_amdgcn_s_setprio(0);
    }

    asm volatile("s_waitcnt lgkmcnt(0)" ::: "memory"); // my LDS reads retired
    __builtin_amdgcn_s_barrier();                      // buf[cur] free for restage
    asm volatile("" ::: "memory");
    __builtin_amdgcn_sched_barrier(0);
  }

  // epilogue: z = (acc + bias) * priors -> f16 zh (or f32)
  // row = m0 + wm*128 + i*16 + g*4 + r ; col = n0 + wn*64 + j*16 + li
  float bv[4];
  #pragma unroll
  for (int j = 0; j < 4; ++j) bv[j] = bias[n0 + wn * 64 + j * 16 + li];
  #pragma unroll
  for (int i = 0; i < 8; ++i) {
    #pragma unroll
    for (int r = 0; r < 4; ++r) {
      size_t row = (size_t)(m0 + wm * 128 + i * 16 + g * 4 + r);
      const float* pp = priors + row * N_COLS + n0 + wn * 64 + li;
      #pragma unroll
      for (int j = 0; j < 4; ++j) {
        float z = (acc[i][j][r] + bv[j]) * pp[j * 16];
        size_t idx = row * N_COLS + n0 + wn * 64 + j * 16 + li;
        if (F16OUT) ((_Float16*)zout)[idx] = (_Float16)z;
        else        ((float*)zout)[idx] = z;
      }
    }
  }
}

// ---------------- sparsemax from f16 z -> f32 out, one wave per row ----------------
__global__ __launch_bounds__(256) void sparsemax_rows_h(
    const _Float16* __restrict__ zh, float* __restrict__ outp)
{
  const int lane = threadIdx.x & 63, wid = threadIdx.x >> 6;
  const size_t row = (size_t)blockIdx.x * 4 + wid;
  const _Float16* p = zh + row * N_COLS + lane * 16;

  f16x8 h0 = *(const f16x8*)(p);
  f16x8 h1 = *(const f16x8*)(p + 8);
  float v[16];
  #pragma unroll
  for (int j = 0; j < 8; ++j) { v[j] = (float)h0[j]; v[8 + j] = (float)h1[j]; }

  float mx = v[0];
  #pragma unroll
  for (int j = 1; j < 16; ++j) mx = fmaxf(mx, v[j]);
  #pragma unroll
  for (int m = 1; m <= 32; m <<= 1) mx = fmaxf(mx, __shfl_xor(mx, m, 64));

  float lo = mx - 1.0f, hi = mx;
  for (int it = 0; it < 12; ++it) {
    float tau = 0.5f * (lo + hi);
    float s = 0.f;
    #pragma unroll
    for (int j = 0; j < 16; ++j) s += fmaxf(v[j] - tau, 0.f);
    #pragma unroll
    for (int m = 1; m <= 32; m <<= 1) s += __shfl_xor(s, m, 64);
    if (s >= 1.f) lo = tau; else hi = tau;
  }
  float tau = lo;
  #pragma unroll
  for (int it = 0; it < 2; ++it) {
    float s = 0.f, k = 0.f;
    #pragma unroll
    for (int j = 0; j < 16; ++j) {
      bool g = v[j] > tau;
      s += g ? v[j] : 0.f;
      k += g ? 1.f : 0.f;
    }
    #pragma unroll
    for (int m = 1; m <= 32; m <<= 1) { s += __shfl_xor(s, m, 64); k += __shfl_xor(k, m, 64); }
    tau = (s - 1.f) / k;   // k >= 1 (row max stays in support)
  }

  float* o = outp + row * N_COLS + lane * 16;
  #pragma unroll
  for (int j = 0; j < 4; ++j) {
    float4 t;
    t.x = fmaxf(v[j * 4 + 0] - tau, 0.f);
    t.y = fmaxf(v[j * 4 + 1] - tau, 0.f);
    t.z = fmaxf(v[j * 4 + 2] - tau, 0.f);
    t.w = fmaxf(v[j * 4 + 3] - tau, 0.f);
    *(float4*)(o + j * 4) = t;
  }
}

// ---------------- sparsemax in place on f32 z (mid path) ----------------
__global__ __launch_bounds__(256) void sparsemax_rows(float* __restrict__ z)
{
  const int lane = threadIdx.x & 63, wid = threadIdx.x >> 6;
  const size_t row = (size_t)blockIdx.x * 4 + wid;
  float* p = z + row * N_COLS;
  float v[16];
  #pragma unroll
  for (int j = 0; j < 4; ++j) {
    float4 t = *(const float4*)(p + j * 256 + lane * 4);
    v[j * 4 + 0] = t.x; v[j * 4 + 1] = t.y; v[j * 4 + 2] = t.z; v[j * 4 + 3] = t.w;
  }
  float mx = v[0];
  #pragma unroll
  for (int j = 1; j < 16; ++j) mx = fmaxf(mx, v[j]);
  #pragma unroll
  for (int m = 1; m <= 32; m <<= 1) mx = fmaxf(mx, __shfl_xor(mx, m, 64));
  float lo = mx - 1.0f, hi = mx;
  for (int it = 0; it < 12; ++it) {
    float tau = 0.5f * (lo + hi);
    float s = 0.f;
    #pragma unroll
    for (int j = 0; j < 16; ++j) s += fmaxf(v[j] - tau, 0.f);
    #pragma unroll
    for (int m = 1; m <= 32; m <<= 1) s += __shfl_xor(s, m, 64);
    if (s >= 1.f) lo = tau; else hi = tau;
  }
  float tau = lo;
  #pragma unroll
  for (int it = 0; it < 2; ++it) {
    float s = 0.f, k = 0.f;
    #pragma unroll
    for (int j = 0; j < 16; ++j) {
      bool g = v[j] > tau;
      s += g ? v[j] : 0.f;
      k += g ? 1.f : 0.f;
    }
    #pragma unroll
    for (int m = 1; m <= 32; m <<= 1) { s += __shfl_xor(s, m, 64); k += __shfl_xor(k, m, 64); }
    tau = (s - 1.f) / k;
  }
  #pragma unroll
  for (int j = 0; j < 4; ++j) {
    float4 t;
    t.x = fmaxf(v[j * 4 + 0] - tau, 0.f);
    t.y = fmaxf(v[j * 4 + 1] - tau, 0.f);
    t.z = fmaxf(v[j * 4 + 2] - tau, 0.f);
    t.w = fmaxf(v[j * 4 + 3] - tau, 0.f);
    *(float4*)(p + j * 256 + lane * 4) = t;
  }
}

// ---------------- FALLBACK GEMM (tiny ws): A reg-staged fp32->f16, dbuf ----------------
__global__ __launch_bounds__(256, 2) void gemm_f16(
    const float* __restrict__ A, const _Float16* __restrict__ Wt,
    const float* __restrict__ bias, const float* __restrict__ priors,
    float* __restrict__ out)
{
  __shared__ char smem[65536];
  const int tid = threadIdx.x;
  const int lane = tid & 63, wid = tid >> 6;
  const int wm = wid >> 1, wnn = wid & 1;
  int orig = blockIdx.x;
  int wgid = (orig & 7) * 512 + (orig >> 3);
  int mb = wgid >> 3, nb = wgid & 7;
  const int m0 = mb * 128, n0 = nb * 128;
  f32x4 acc[4][4];
  #pragma unroll
  for (int i = 0; i < 4; ++i)
    #pragma unroll
    for (int j = 0; j < 4; ++j) acc[i][j] = (f32x4){0.f, 0.f, 0.f, 0.f};
  float4 areg[8];
  auto loadA = [&](int kt) {
    #pragma unroll
    for (int j = 0; j < 8; ++j) {
      int f = j * 256 + tid;
      int ml = f >> 4, k4 = (f & 15) << 2;
      areg[j] = *(const float4*)(A + (size_t)(m0 + ml) * K_DIM + kt * 64 + k4);
    }
  };
  auto storeA = [&](int buf) {
    int base = buf * 16384;
    #pragma unroll
    for (int j = 0; j < 8; ++j) {
      int f = j * 256 + tid;
      int ml = f >> 4, k4 = (f & 15) << 2;
      int off = ml * 128 + ((k4 * 2) ^ ((ml & 7) << 4));
      union { _Float16 h[4]; uint2 u; } p;
      p.h[0] = (_Float16)areg[j].x; p.h[1] = (_Float16)areg[j].y;
      p.h[2] = (_Float16)areg[j].z; p.h[3] = (_Float16)areg[j].w;
      *(uint2*)(&smem[base + off]) = p.u;
    }
  };
  auto issueB = [&](int kt, int buf) {
    int base = 32768 + buf * 16384;
    #pragma unroll
    for (int t4 = 0; t4 < 4; ++t4) {
      int ch = t4 * 256 + tid;
      int nl = ch >> 3, c = ch & 7;
      const char* src = (const char*)Wt + ((size_t)(n0 + nl) * K_DIM + kt * 64) * 2
          + ((c * 16) ^ ((nl & 7) << 4));
      __builtin_amdgcn_global_load_lds(
          (const __attribute__((address_space(1))) unsigned int*)src,
          (__attribute__((address_space(3))) unsigned int*)(&smem[base + ch * 16]),
          16, 0, 0);
    }
  };
  loadA(0); issueB(0, 0); storeA(0);
  __syncthreads();
  for (int kt = 0; kt < 16; ++kt) {
    int curb = kt & 1, nxt = curb ^ 1;
    if (kt < 15) { loadA(kt + 1); issueB(kt + 1, nxt); }
    int ab = curb * 16384, bb = 32768 + curb * 16384;
    #pragma unroll
    for (int kc = 0; kc < 2; ++kc) {
      int k2 = (kc * 32 + ((lane >> 4) * 8)) * 2;
      f16x8 af[4], bfr[4];
      #pragma unroll
      for (int fm = 0; fm < 4; ++fm) {
        int rl2 = wm * 64 + fm * 16 + (lane & 15);
        af[fm] = *(const f16x8*)(&smem[ab + rl2 * 128 + (k2 ^ ((rl2 & 7) << 4))]);
      }
      #pragma unroll
      for (int fn = 0; fn < 4; ++fn) {
        int nl = wnn * 64 + fn * 16 + (lane & 15);
        bfr[fn] = *(const f16x8*)(&smem[bb + nl * 128 + (k2 ^ ((nl & 7) << 4))]);
      }
      #pragma unroll
      for (int fm = 0; fm < 4; ++fm)
        #pragma unroll
        for (int fn = 0; fn < 4; ++fn)
          acc[fm][fn] = __builtin_amdgcn_mfma_f32_16x16x32_f16(af[fm], bfr[fn], acc[fm][fn], 0, 0, 0);
    }
    if (kt < 15) storeA(nxt);
    __syncthreads();
  }
  #pragma unroll
  for (int fn = 0; fn < 4; ++fn) {
    int col = n0 + wnn * 64 + fn * 16 + (lane & 15);
    float bvv = bias[col];
    #pragma unroll
    for (int fm = 0; fm < 4; ++fm) {
      int row0 = m0 + wm * 64 + fm * 16 + ((lane >> 4) << 2);
      #pragma unroll
      for (int r = 0; r < 4; ++r) {
        size_t idx = (size_t)(row0 + r) * N_COLS + col;
        out[idx] = (acc[fm][fn][r] + bvv) * priors[idx];
      }
    }
  }
}

// ---------------- launch ----------------
extern "C" void kernel_launch(void* const* d_in, const int* in_sizes, int n_in,
                              void* d_out, int out_size, void* d_ws, size_t ws_size,
                              hipStream_t stream) {
  const float* inputs = (const float*)d_in[0];
  const float* priors = (const float*)d_in[1];
  const float* W      = (const float*)d_in[2];
  const float* gamma  = (const float*)d_in[3];
  const float* beta   = (const float*)d_in[4];
  const float* mean   = (const float*)d_in[5];
  const float* var    = (const float*)d_in[6];
  float* out = (float*)d_out;

  char* ws = (char*)d_ws;
  float* bias  = (float*)ws;                 // 4 KB
  float* scale = (float*)(ws + 4096);        // 4 KB
  _Float16* Wt = (_Float16*)(ws + 8192);     // 2 MB, [N][K] transposed+scaled
  const size_t AF_OFF = 8192 + (size_t)N_COLS * K_DIM * 2;          // 2105344
  _Float16* Af = (_Float16*)(ws + AF_OFF);   // 134 MB, [M][K] f16
  const size_t ZH_OFF = AF_OFF + (size_t)M_ROWS * K_DIM * 2;        // 136323072
  _Float16* zh = (_Float16*)(ws + ZH_OFF);   // 134 MB, [M][N] f16 z
  const size_t need  = ZH_OFF;
  const size_t need2 = ZH_OFF + (size_t)M_ROWS * N_COLS * 2;

  prep_scale_bias<<<4, 256, 0, stream>>>(gamma, beta, mean, var, bias, scale);
  prep_wt<<<dim3(16, 16), 256, 0, stream>>>(W, scale, Wt);

  if (ws_size >= need2) {
    conv_a_f16<<<2048, 256, 0, stream>>>(inputs, Af);
    gemm_256<1><<<1024, 512, 0, stream>>>(Af, Wt, bias, priors, zh);
    sparsemax_rows_h<<<16384, 256, 0, stream>>>(zh, out);
  } else if (ws_size >= need) {
    conv_a_f16<<<2048, 256, 0, stream>>>(inputs, Af);
    gemm_256<0><<<1024, 512, 0, stream>>>(Af, Wt, bias, priors, out);
    sparsemax_rows<<<16384, 256, 0, stream>>>(out);
  } else {
    gemm_f16<<<4096, 256, 0, stream>>>(inputs, Wt, bias, priors, out);
    sparsemax_rows<<<16384, 256, 0, stream>>>(out);
  }
}

// Round 16
// 402.134 us; speedup vs baseline: 1.0456x; 1.0153x over previous
//
#include <hip/hip_runtime.h>
#include <cstdint>
#include <cstddef>

#define M_ROWS 65536
#define N_COLS 1024
#define K_DIM  1024

typedef _Float16 f16x8 __attribute__((ext_vector_type(8)));
typedef float f32x4 __attribute__((ext_vector_type(4)));

// ---------------- prep: scale/bias ----------------
__global__ __launch_bounds__(256) void prep_scale_bias(
    const float* __restrict__ gamma, const float* __restrict__ beta,
    const float* __restrict__ mean, const float* __restrict__ var,
    float* __restrict__ bias, float* __restrict__ scale)
{
  int i = blockIdx.x * 256 + threadIdx.x;
  if (i < N_COLS) {
    float s = gamma[i] * rsqrtf(var[i] + 1e-3f);
    scale[i] = s;
    bias[i] = beta[i] - mean[i] * s;
  }
}

// ---------------- prep: W -> Wt (transposed, scaled, f16) ----------------
__global__ __launch_bounds__(256) void prep_wt(
    const float* __restrict__ W, const float* __restrict__ scale,
    _Float16* __restrict__ Wt)
{
  __shared__ float tile[64][68];
  int k0 = blockIdx.x * 64, n0 = blockIdx.y * 64;
  int t = threadIdx.x;
  int kr = t >> 2, q = t & 3;
  #pragma unroll
  for (int j = 0; j < 4; ++j) {
    float4 v = *(const float4*)(W + (size_t)(k0 + kr) * N_COLS + n0 + q * 16 + j * 4);
    *(float4*)(&tile[kr][q * 16 + j * 4]) = v;
  }
  __syncthreads();
  int nr = t >> 2;
  float sn = scale[n0 + nr];
  __align__(16) _Float16 h[16];
  #pragma unroll
  for (int j = 0; j < 16; ++j)
    h[j] = (_Float16)(tile[q * 16 + j][nr] * sn);
  uint4* dst = (uint4*)(Wt + (size_t)(n0 + nr) * K_DIM + k0 + q * 16);
  dst[0] = *(uint4*)(&h[0]);
  dst[1] = *(uint4*)(&h[8]);
}

// ---------------- prep: A (fp32) -> Af (f16), grid-stride, vectorized ----------------
__global__ __launch_bounds__(256) void conv_a_f16(
    const float* __restrict__ A, _Float16* __restrict__ Af)
{
  const size_t total8 = (size_t)M_ROWS * K_DIM / 8;
  size_t i = (size_t)blockIdx.x * 256 + threadIdx.x;
  const size_t stride = (size_t)gridDim.x * 256;
  for (; i < total8; i += stride) {
    float4 a = *(const float4*)(A + i * 8);
    float4 b = *(const float4*)(A + i * 8 + 4);
    union { _Float16 h[8]; uint4 u; } p;
    p.h[0] = (_Float16)a.x; p.h[1] = (_Float16)a.y;
    p.h[2] = (_Float16)a.z; p.h[3] = (_Float16)a.w;
    p.h[4] = (_Float16)b.x; p.h[5] = (_Float16)b.y;
    p.h[6] = (_Float16)b.z; p.h[7] = (_Float16)b.w;
    *(uint4*)(Af + i * 8) = p.u;
  }
}

// ---------------- 256x256 8-wave GEMM (R11 schedule, fragment-reuse inner loop) ----------------
// 512 threads = 8 waves (2M x 4N); per wave 128x64 output, acc[8][4] in AGPRs.
// LDS 128 KB dbuf, m97-proven 128B rows + XOR swizzle; wave-split staging issued
// early in the body (R11). Inner loop restructured: 2 kc x {8 af + 4 bf reads ->
// 32 MFMA} instead of 4 quadrants x {8 af + 4 bf -> 16 MFMA}: halves LDS read
// traffic (48->24 KB/wave/K-tile; 384->192 KB/CU, below the MFMA pipe's cycles).
template<int F16OUT>
__global__ __launch_bounds__(512, 2) void gemm_256(
    const _Float16* __restrict__ Af, const _Float16* __restrict__ Wt,
    const float* __restrict__ bias, const float* __restrict__ priors,
    void* __restrict__ zout)
{
  __shared__ char smem[131072];   // buf b: A @ b*65536, B @ b*65536+32768
  const int tid = threadIdx.x;
  const int lane = tid & 63, wid = tid >> 6;
  const int wm = wid >> 2, wn = wid & 3;
  const int li = lane & 15, g = lane >> 4;

  // bijective XCD swizzle (nwg=1024, 1024%8==0)
  int orig = blockIdx.x;
  int wgid = (orig & 7) * 128 + (orig >> 3);
  int mb = wgid >> 2, nb = wgid & 3;
  const int m0 = mb * 256, n0 = nb * 256;

  f32x4 acc[8][4];
  #pragma unroll
  for (int i = 0; i < 8; ++i)
    #pragma unroll
    for (int j = 0; j < 4; ++j) acc[i][j] = (f32x4){0.f, 0.f, 0.f, 0.f};

  // wave-split staging shares (proven R11)
  const int arow0 = wm * 128 + wn * 32;                          // my 32 A-rows (local)
  const int bcol0 = (wn >> 1) * 128 + (wm * 2 + (wn & 1)) * 32;  // my 32 B-cols (local)

  auto stageA = [&](int kt, int buf) {
    #pragma unroll
    for (int j = 0; j < 4; ++j) {
      int ch = j * 64 + lane;            // 256 chunks: 32 rows x 8
      int rloc = ch >> 3, c = ch & 7;
      int row = arow0 + rloc;
      const char* src = (const char*)Af + ((size_t)(m0 + row) * K_DIM + kt * 64) * 2
                        + ((c * 16) ^ ((row & 7) << 4));
      __builtin_amdgcn_global_load_lds(
          (const __attribute__((address_space(1))) unsigned int*)src,
          (__attribute__((address_space(3))) unsigned int*)(&smem[buf * 65536 + arow0 * 128 + ch * 16]),
          16, 0, 0);
    }
  };
  auto stageB = [&](int kt, int buf) {
    #pragma unroll
    for (int j = 0; j < 4; ++j) {
      int ch = j * 64 + lane;
      int rloc = ch >> 3, c = ch & 7;
      int col = bcol0 + rloc;
      const char* src = (const char*)Wt + ((size_t)(n0 + col) * K_DIM + kt * 64) * 2
                        + ((c * 16) ^ ((col & 7) << 4));
      __builtin_amdgcn_global_load_lds(
          (const __attribute__((address_space(1))) unsigned int*)src,
          (__attribute__((address_space(3))) unsigned int*)(&smem[buf * 65536 + 32768 + bcol0 * 128 + ch * 16]),
          16, 0, 0);
    }
  };

  const int aswz = (li & 7) << 4;

  // prologue: stage ktile 0 into buf 0
  stageA(0, 0);
  stageB(0, 0);

  for (int t = 0; t < 16; ++t) {
    asm volatile("s_waitcnt vmcnt(0)" ::: "memory");   // stage loads for ktile t landed
    __builtin_amdgcn_s_barrier();                      // everyone's landed
    asm volatile("" ::: "memory");
    __builtin_amdgcn_sched_barrier(0);

    const int cur = t & 1;
    const int abase = cur * 65536, bbase = cur * 65536 + 32768;
    const int ktn = (t + 1 < 16) ? t + 1 : 15;         // clamped (redundant tail stage harmless)

    #pragma unroll
    for (int kc = 0; kc < 2; ++kc) {
      if (kc == 0) stageA(ktn, cur ^ 1);               // early issue -> latency cover
      if (kc == 1) stageB(ktn, cur ^ 1);
      const int koff = (kc * 64 + g * 16) ^ aswz;
      f16x8 af[8], bf[4];
      #pragma unroll
      for (int fr = 0; fr < 8; ++fr) {
        int row = wm * 128 + fr * 16 + li;
        af[fr] = *(const f16x8*)(&smem[abase + row * 128 + koff]);
      }
      #pragma unroll
      for (int fc = 0; fc < 4; ++fc) {
        int col = wn * 64 + fc * 16 + li;
        bf[fc] = *(const f16x8*)(&smem[bbase + col * 128 + koff]);
      }
      __builtin_amdgcn_s_setprio(1);
      #pragma unroll
      for (int fr = 0; fr < 8; ++fr)
        #pragma unroll
        for (int fc = 0; fc < 4; ++fc)
          acc[fr][fc] = __builtin_amdgcn_mfma_f32_16x16x32_f16(
              af[fr], bf[fc], acc[fr][fc], 0, 0, 0);
      __builtin_amdgcn_s_setprio(0);
    }

    asm volatile("s_waitcnt lgkmcnt(0)" ::: "memory"); // my LDS reads retired
    __builtin_amdgcn_s_barrier();                      // buf[cur] free for restage
    asm volatile("" ::: "memory");
    __builtin_amdgcn_sched_barrier(0);
  }

  // epilogue: z = (acc + bias) * priors -> f16 zh (or f32)
  // row = m0 + wm*128 + i*16 + g*4 + r ; col = n0 + wn*64 + j*16 + li
  float bv[4];
  #pragma unroll
  for (int j = 0; j < 4; ++j) bv[j] = bias[n0 + wn * 64 + j * 16 + li];
  #pragma unroll
  for (int i = 0; i < 8; ++i) {
    #pragma unroll
    for (int r = 0; r < 4; ++r) {
      size_t row = (size_t)(m0 + wm * 128 + i * 16 + g * 4 + r);
      const float* pp = priors + row * N_COLS + n0 + wn * 64 + li;
      #pragma unroll
      for (int j = 0; j < 4; ++j) {
        float z = (acc[i][j][r] + bv[j]) * pp[j * 16];
        size_t idx = row * N_COLS + n0 + wn * 64 + j * 16 + li;
        if (F16OUT) ((_Float16*)zout)[idx] = (_Float16)z;
        else        ((float*)zout)[idx] = z;
      }
    }
  }
}

// ---------------- sparsemax from f16 z -> f32 out, one wave per row ----------------
__global__ __launch_bounds__(256) void sparsemax_rows_h(
    const _Float16* __restrict__ zh, float* __restrict__ outp)
{
  const int lane = threadIdx.x & 63, wid = threadIdx.x >> 6;
  const size_t row = (size_t)blockIdx.x * 4 + wid;
  const _Float16* p = zh + row * N_COLS + lane * 16;

  f16x8 h0 = *(const f16x8*)(p);
  f16x8 h1 = *(const f16x8*)(p + 8);
  float v[16];
  #pragma unroll
  for (int j = 0; j < 8; ++j) { v[j] = (float)h0[j]; v[8 + j] = (float)h1[j]; }

  float mx = v[0];
  #pragma unroll
  for (int j = 1; j < 16; ++j) mx = fmaxf(mx, v[j]);
  #pragma unroll
  for (int m = 1; m <= 32; m <<= 1) mx = fmaxf(mx, __shfl_xor(mx, m, 64));

  float lo = mx - 1.0f, hi = mx;
  for (int it = 0; it < 12; ++it) {
    float tau = 0.5f * (lo + hi);
    float s = 0.f;
    #pragma unroll
    for (int j = 0; j < 16; ++j) s += fmaxf(v[j] - tau, 0.f);
    #pragma unroll
    for (int m = 1; m <= 32; m <<= 1) s += __shfl_xor(s, m, 64);
    if (s >= 1.f) lo = tau; else hi = tau;
  }
  float tau = lo;
  #pragma unroll
  for (int it = 0; it < 2; ++it) {
    float s = 0.f, k = 0.f;
    #pragma unroll
    for (int j = 0; j < 16; ++j) {
      bool g = v[j] > tau;
      s += g ? v[j] : 0.f;
      k += g ? 1.f : 0.f;
    }
    #pragma unroll
    for (int m = 1; m <= 32; m <<= 1) { s += __shfl_xor(s, m, 64); k += __shfl_xor(k, m, 64); }
    tau = (s - 1.f) / k;   // k >= 1 (row max stays in support)
  }

  float* o = outp + row * N_COLS + lane * 16;
  #pragma unroll
  for (int j = 0; j < 4; ++j) {
    float4 t;
    t.x = fmaxf(v[j * 4 + 0] - tau, 0.f);
    t.y = fmaxf(v[j * 4 + 1] - tau, 0.f);
    t.z = fmaxf(v[j * 4 + 2] - tau, 0.f);
    t.w = fmaxf(v[j * 4 + 3] - tau, 0.f);
    *(float4*)(o + j * 4) = t;
  }
}

// ---------------- sparsemax in place on f32 z (mid path) ----------------
__global__ __launch_bounds__(256) void sparsemax_rows(float* __restrict__ z)
{
  const int lane = threadIdx.x & 63, wid = threadIdx.x >> 6;
  const size_t row = (size_t)blockIdx.x * 4 + wid;
  float* p = z + row * N_COLS;
  float v[16];
  #pragma unroll
  for (int j = 0; j < 4; ++j) {
    float4 t = *(const float4*)(p + j * 256 + lane * 4);
    v[j * 4 + 0] = t.x; v[j * 4 + 1] = t.y; v[j * 4 + 2] = t.z; v[j * 4 + 3] = t.w;
  }
  float mx = v[0];
  #pragma unroll
  for (int j = 1; j < 16; ++j) mx = fmaxf(mx, v[j]);
  #pragma unroll
  for (int m = 1; m <= 32; m <<= 1) mx = fmaxf(mx, __shfl_xor(mx, m, 64));
  float lo = mx - 1.0f, hi = mx;
  for (int it = 0; it < 12; ++it) {
    float tau = 0.5f * (lo + hi);
    float s = 0.f;
    #pragma unroll
    for (int j = 0; j < 16; ++j) s += fmaxf(v[j] - tau, 0.f);
    #pragma unroll
    for (int m = 1; m <= 32; m <<= 1) s += __shfl_xor(s, m, 64);
    if (s >= 1.f) lo = tau; else hi = tau;
  }
  float tau = lo;
  #pragma unroll
  for (int it = 0; it < 2; ++it) {
    float s = 0.f, k = 0.f;
    #pragma unroll
    for (int j = 0; j < 16; ++j) {
      bool g = v[j] > tau;
      s += g ? v[j] : 0.f;
      k += g ? 1.f : 0.f;
    }
    #pragma unroll
    for (int m = 1; m <= 32; m <<= 1) { s += __shfl_xor(s, m, 64); k += __shfl_xor(k, m, 64); }
    tau = (s - 1.f) / k;
  }
  #pragma unroll
  for (int j = 0; j < 4; ++j) {
    float4 t;
    t.x = fmaxf(v[j * 4 + 0] - tau, 0.f);
    t.y = fmaxf(v[j * 4 + 1] - tau, 0.f);
    t.z = fmaxf(v[j * 4 + 2] - tau, 0.f);
    t.w = fmaxf(v[j * 4 + 3] - tau, 0.f);
    *(float4*)(p + j * 256 + lane * 4) = t;
  }
}

// ---------------- FALLBACK GEMM (tiny ws): A reg-staged fp32->f16, dbuf ----------------
__global__ __launch_bounds__(256, 2) void gemm_f16(
    const float* __restrict__ A, const _Float16* __restrict__ Wt,
    const float* __restrict__ bias, const float* __restrict__ priors,
    float* __restrict__ out)
{
  __shared__ char smem[65536];
  const int tid = threadIdx.x;
  const int lane = tid & 63, wid = tid >> 6;
  const int wm = wid >> 1, wnn = wid & 1;
  int orig = blockIdx.x;
  int wgid = (orig & 7) * 512 + (orig >> 3);
  int mb = wgid >> 3, nb = wgid & 7;
  const int m0 = mb * 128, n0 = nb * 128;
  f32x4 acc[4][4];
  #pragma unroll
  for (int i = 0; i < 4; ++i)
    #pragma unroll
    for (int j = 0; j < 4; ++j) acc[i][j] = (f32x4){0.f, 0.f, 0.f, 0.f};
  float4 areg[8];
  auto loadA = [&](int kt) {
    #pragma unroll
    for (int j = 0; j < 8; ++j) {
      int f = j * 256 + tid;
      int ml = f >> 4, k4 = (f & 15) << 2;
      areg[j] = *(const float4*)(A + (size_t)(m0 + ml) * K_DIM + kt * 64 + k4);
    }
  };
  auto storeA = [&](int buf) {
    int base = buf * 16384;
    #pragma unroll
    for (int j = 0; j < 8; ++j) {
      int f = j * 256 + tid;
      int ml = f >> 4, k4 = (f & 15) << 2;
      int off = ml * 128 + ((k4 * 2) ^ ((ml & 7) << 4));
      union { _Float16 h[4]; uint2 u; } p;
      p.h[0] = (_Float16)areg[j].x; p.h[1] = (_Float16)areg[j].y;
      p.h[2] = (_Float16)areg[j].z; p.h[3] = (_Float16)areg[j].w;
      *(uint2*)(&smem[base + off]) = p.u;
    }
  };
  auto issueB = [&](int kt, int buf) {
    int base = 32768 + buf * 16384;
    #pragma unroll
    for (int t4 = 0; t4 < 4; ++t4) {
      int ch = t4 * 256 + tid;
      int nl = ch >> 3, c = ch & 7;
      const char* src = (const char*)Wt + ((size_t)(n0 + nl) * K_DIM + kt * 64) * 2
          + ((c * 16) ^ ((nl & 7) << 4));
      __builtin_amdgcn_global_load_lds(
          (const __attribute__((address_space(1))) unsigned int*)src,
          (__attribute__((address_space(3))) unsigned int*)(&smem[base + ch * 16]),
          16, 0, 0);
    }
  };
  loadA(0); issueB(0, 0); storeA(0);
  __syncthreads();
  for (int kt = 0; kt < 16; ++kt) {
    int curb = kt & 1, nxt = curb ^ 1;
    if (kt < 15) { loadA(kt + 1); issueB(kt + 1, nxt); }
    int ab = curb * 16384, bb = 32768 + curb * 16384;
    #pragma unroll
    for (int kc = 0; kc < 2; ++kc) {
      int k2 = (kc * 32 + ((lane >> 4) * 8)) * 2;
      f16x8 af[4], bfr[4];
      #pragma unroll
      for (int fm = 0; fm < 4; ++fm) {
        int rl2 = wm * 64 + fm * 16 + (lane & 15);
        af[fm] = *(const f16x8*)(&smem[ab + rl2 * 128 + (k2 ^ ((rl2 & 7) << 4))]);
      }
      #pragma unroll
      for (int fn = 0; fn < 4; ++fn) {
        int nl = wnn * 64 + fn * 16 + (lane & 15);
        bfr[fn] = *(const f16x8*)(&smem[bb + nl * 128 + (k2 ^ ((nl & 7) << 4))]);
      }
      #pragma unroll
      for (int fm = 0; fm < 4; ++fm)
        #pragma unroll
        for (int fn = 0; fn < 4; ++fn)
          acc[fm][fn] = __builtin_amdgcn_mfma_f32_16x16x32_f16(af[fm], bfr[fn], acc[fm][fn], 0, 0, 0);
    }
    if (kt < 15) storeA(nxt);
    __syncthreads();
  }
  #pragma unroll
  for (int fn = 0; fn < 4; ++fn) {
    int col = n0 + wnn * 64 + fn * 16 + (lane & 15);
    float bvv = bias[col];
    #pragma unroll
    for (int fm = 0; fm < 4; ++fm) {
      int row0 = m0 + wm * 64 + fm * 16 + ((lane >> 4) << 2);
      #pragma unroll
      for (int r = 0; r < 4; ++r) {
        size_t idx = (size_t)(row0 + r) * N_COLS + col;
        out[idx] = (acc[fm][fn][r] + bvv) * priors[idx];
      }
    }
  }
}

// ---------------- launch ----------------
extern "C" void kernel_launch(void* const* d_in, const int* in_sizes, int n_in,
                              void* d_out, int out_size, void* d_ws, size_t ws_size,
                              hipStream_t stream) {
  const float* inputs = (const float*)d_in[0];
  const float* priors = (const float*)d_in[1];
  const float* W      = (const float*)d_in[2];
  const float* gamma  = (const float*)d_in[3];
  const float* beta   = (const float*)d_in[4];
  const float* mean   = (const float*)d_in[5];
  const float* var    = (const float*)d_in[6];
  float* out = (float*)d_out;

  char* ws = (char*)d_ws;
  float* bias  = (float*)ws;                 // 4 KB
  float* scale = (float*)(ws + 4096);        // 4 KB
  _Float16* Wt = (_Float16*)(ws + 8192);     // 2 MB, [N][K] transposed+scaled
  const size_t AF_OFF = 8192 + (size_t)N_COLS * K_DIM * 2;          // 2105344
  _Float16* Af = (_Float16*)(ws + AF_OFF);   // 134 MB, [M][K] f16
  const size_t ZH_OFF = AF_OFF + (size_t)M_ROWS * K_DIM * 2;        // 136323072
  _Float16* zh = (_Float16*)(ws + ZH_OFF);   // 134 MB, [M][N] f16 z
  const size_t need  = ZH_OFF;
  const size_t need2 = ZH_OFF + (size_t)M_ROWS * N_COLS * 2;

  prep_scale_bias<<<4, 256, 0, stream>>>(gamma, beta, mean, var, bias, scale);
  prep_wt<<<dim3(16, 16), 256, 0, stream>>>(W, scale, Wt);

  if (ws_size >= need2) {
    conv_a_f16<<<2048, 256, 0, stream>>>(inputs, Af);
    gemm_256<1><<<1024, 512, 0, stream>>>(Af, Wt, bias, priors, zh);
    sparsemax_rows_h<<<16384, 256, 0, stream>>>(zh, out);
  } else if (ws_size >= need) {
    conv_a_f16<<<2048, 256, 0, stream>>>(inputs, Af);
    gemm_256<0><<<1024, 512, 0, stream>>>(Af, Wt, bias, priors, out);
    sparsemax_rows<<<16384, 256, 0, stream>>>(out);
  } else {
    gemm_f16<<<4096, 256, 0, stream>>>(inputs, Wt, bias, priors, out);
    sparsemax_rows<<<16384, 256, 0, stream>>>(out);
  }
}

// Round 17
// 367.891 us; speedup vs baseline: 1.1429x; 1.0931x over previous
//
#include <hip/hip_runtime.h>
#include <cstdint>
#include <cstddef>

#define M_ROWS 65536
#define N_COLS 1024
#define K_DIM  1024

typedef _Float16 f16x8 __attribute__((ext_vector_type(8)));
typedef float f32x4 __attribute__((ext_vector_type(4)));

// ---------------- prep: scale/bias ----------------
__global__ __launch_bounds__(256) void prep_scale_bias(
    const float* __restrict__ gamma, const float* __restrict__ beta,
    const float* __restrict__ mean, const float* __restrict__ var,
    float* __restrict__ bias, float* __restrict__ scale)
{
  int i = blockIdx.x * 256 + threadIdx.x;
  if (i < N_COLS) {
    float s = gamma[i] * rsqrtf(var[i] + 1e-3f);
    scale[i] = s;
    bias[i] = beta[i] - mean[i] * s;
  }
}

// ---------------- prep: W -> Wt (transposed, scaled, f16) ----------------
__global__ __launch_bounds__(256) void prep_wt(
    const float* __restrict__ W, const float* __restrict__ scale,
    _Float16* __restrict__ Wt)
{
  __shared__ float tile[64][68];
  int k0 = blockIdx.x * 64, n0 = blockIdx.y * 64;
  int t = threadIdx.x;
  int kr = t >> 2, q = t & 3;
  #pragma unroll
  for (int j = 0; j < 4; ++j) {
    float4 v = *(const float4*)(W + (size_t)(k0 + kr) * N_COLS + n0 + q * 16 + j * 4);
    *(float4*)(&tile[kr][q * 16 + j * 4]) = v;
  }
  __syncthreads();
  int nr = t >> 2;
  float sn = scale[n0 + nr];
  __align__(16) _Float16 h[16];
  #pragma unroll
  for (int j = 0; j < 16; ++j)
    h[j] = (_Float16)(tile[q * 16 + j][nr] * sn);
  uint4* dst = (uint4*)(Wt + (size_t)(n0 + nr) * K_DIM + k0 + q * 16);
  dst[0] = *(uint4*)(&h[0]);
  dst[1] = *(uint4*)(&h[8]);
}

// ---------------- 256x256 8-wave GEMM with FUSED A fp32->f16 staging ----------------
// R16 structure (fragment-reuse inner loop, wave-split B staging, XOR swizzle) with
// conv_a folded in: A is read fp32 from HBM into regs (issued kc=0, full body of
// latency cover), converted to f16, and ds_written (swizzled) into buf^1 after the
// trailing barrier. Top-of-tile wait: vmcnt(0) lgkmcnt(0) + barrier (publishes writes).
template<int F16OUT>
__global__ __launch_bounds__(512, 2) void gemm_256c(
    const float* __restrict__ A, const _Float16* __restrict__ Wt,
    const float* __restrict__ bias, const float* __restrict__ priors,
    void* __restrict__ zout)
{
  __shared__ char smem[131072];   // buf b: A @ b*65536, B @ b*65536+32768
  const int tid = threadIdx.x;
  const int lane = tid & 63, wid = tid >> 6;
  const int wm = wid >> 2, wn = wid & 3;
  const int li = lane & 15, g = lane >> 4;

  // bijective XCD swizzle (nwg=1024, 1024%8==0)
  int orig = blockIdx.x;
  int wgid = (orig & 7) * 128 + (orig >> 3);
  int mb = wgid >> 2, nb = wgid & 3;
  const int m0 = mb * 256, n0 = nb * 256;

  f32x4 acc[8][4];
  #pragma unroll
  for (int i = 0; i < 8; ++i)
    #pragma unroll
    for (int j = 0; j < 4; ++j) acc[i][j] = (f32x4){0.f, 0.f, 0.f, 0.f};

  // wave-split staging shares (proven R11/R16)
  const int arow0 = wm * 128 + wn * 32;                          // my 32 A-rows (local)
  const int bcol0 = (wn >> 1) * 128 + (wm * 2 + (wn & 1)) * 32;  // my 32 B-cols (local)

  // A: 32 rows x 64 k fp32 per wave = 256 chunks of 8 f16; per lane 4 chunks (2 float4 each)
  float4 areg[4][2];
  auto loadA = [&](int kt) {
    #pragma unroll
    for (int j = 0; j < 4; ++j) {
      int ch = j * 64 + lane;
      int rloc = ch >> 3, c = ch & 7;
      const float* src = A + (size_t)(m0 + arow0 + rloc) * K_DIM + kt * 64 + c * 8;
      areg[j][0] = *(const float4*)(src);
      areg[j][1] = *(const float4*)(src + 4);
    }
  };
  auto storeA = [&](int buf) {
    #pragma unroll
    for (int j = 0; j < 4; ++j) {
      int ch = j * 64 + lane;
      int rloc = ch >> 3, c = ch & 7;
      int row = arow0 + rloc;
      union { _Float16 h[8]; uint4 u; } p;
      p.h[0] = (_Float16)areg[j][0].x; p.h[1] = (_Float16)areg[j][0].y;
      p.h[2] = (_Float16)areg[j][0].z; p.h[3] = (_Float16)areg[j][0].w;
      p.h[4] = (_Float16)areg[j][1].x; p.h[5] = (_Float16)areg[j][1].y;
      p.h[6] = (_Float16)areg[j][1].z; p.h[7] = (_Float16)areg[j][1].w;
      int off = row * 128 + ((c * 16) ^ ((row & 7) << 4));   // swizzled dest (ds_write path)
      *(uint4*)(&smem[buf * 65536 + off]) = p.u;
    }
  };
  auto stageB = [&](int kt, int buf) {
    #pragma unroll
    for (int j = 0; j < 4; ++j) {
      int ch = j * 64 + lane;
      int rloc = ch >> 3, c = ch & 7;
      int col = bcol0 + rloc;
      const char* src = (const char*)Wt + ((size_t)(n0 + col) * K_DIM + kt * 64) * 2
                        + ((c * 16) ^ ((col & 7) << 4));   // inverse-swizzled source (rule 21)
      __builtin_amdgcn_global_load_lds(
          (const __attribute__((address_space(1))) unsigned int*)src,
          (__attribute__((address_space(3))) unsigned int*)(&smem[buf * 65536 + 32768 + bcol0 * 128 + ch * 16]),
          16, 0, 0);
    }
  };

  const int aswz = (li & 7) << 4;

  // prologue: tile 0 into buf 0
  loadA(0);
  stageB(0, 0);
  storeA(0);   // compiler waits A-reg vmcnt automatically

  for (int t = 0; t < 16; ++t) {
    // B gloads for tile t done + my ds_writes drained; barrier publishes both
    asm volatile("s_waitcnt vmcnt(0) lgkmcnt(0)" ::: "memory");
    __builtin_amdgcn_s_barrier();
    asm volatile("" ::: "memory");
    __builtin_amdgcn_sched_barrier(0);

    const int cur = t & 1;
    const int abase = cur * 65536, bbase = cur * 65536 + 32768;
    const int ktn = (t + 1 < 16) ? t + 1 : 15;   // clamped (redundant tail work harmless)

    #pragma unroll
    for (int kc = 0; kc < 2; ++kc) {
      if (kc == 0) loadA(ktn);                   // A regs: full body of latency cover
      if (kc == 1) stageB(ktn, cur ^ 1);
      const int koff = (kc * 64 + g * 16) ^ aswz;
      f16x8 af[8], bf[4];
      #pragma unroll
      for (int fr = 0; fr < 8; ++fr) {
        int row = wm * 128 + fr * 16 + li;
        af[fr] = *(const f16x8*)(&smem[abase + row * 128 + koff]);
      }
      #pragma unroll
      for (int fc = 0; fc < 4; ++fc) {
        int col = wn * 64 + fc * 16 + li;
        bf[fc] = *(const f16x8*)(&smem[bbase + col * 128 + koff]);
      }
      __builtin_amdgcn_s_setprio(1);
      #pragma unroll
      for (int fr = 0; fr < 8; ++fr)
        #pragma unroll
        for (int fc = 0; fc < 4; ++fc)
          acc[fr][fc] = __builtin_amdgcn_mfma_f32_16x16x32_f16(
              af[fr], bf[fc], acc[fr][fc], 0, 0, 0);
      __builtin_amdgcn_s_setprio(0);
    }

    asm volatile("s_waitcnt lgkmcnt(0)" ::: "memory"); // my LDS reads retired
    __builtin_amdgcn_s_barrier();                      // all waves done with buf[cur]
    asm volatile("" ::: "memory");
    __builtin_amdgcn_sched_barrier(0);
    if (t < 15) storeA(cur ^ 1);                       // cvt + swizzled ds_write A(t+1)
  }

  // epilogue: z = (acc + bias) * priors -> f16 zh (or f32)
  float bv[4];
  #pragma unroll
  for (int j = 0; j < 4; ++j) bv[j] = bias[n0 + wn * 64 + j * 16 + li];
  #pragma unroll
  for (int i = 0; i < 8; ++i) {
    #pragma unroll
    for (int r = 0; r < 4; ++r) {
      size_t row = (size_t)(m0 + wm * 128 + i * 16 + g * 4 + r);
      const float* pp = priors + row * N_COLS + n0 + wn * 64 + li;
      #pragma unroll
      for (int j = 0; j < 4; ++j) {
        float z = (acc[i][j][r] + bv[j]) * pp[j * 16];
        size_t idx = row * N_COLS + n0 + wn * 64 + j * 16 + li;
        if (F16OUT) ((_Float16*)zout)[idx] = (_Float16)z;
        else        ((float*)zout)[idx] = z;
      }
    }
  }
}

// ---------------- sparsemax from f16 z -> f32 out, one wave per row ----------------
__global__ __launch_bounds__(256) void sparsemax_rows_h(
    const _Float16* __restrict__ zh, float* __restrict__ outp)
{
  const int lane = threadIdx.x & 63, wid = threadIdx.x >> 6;
  const size_t row = (size_t)blockIdx.x * 4 + wid;
  const _Float16* p = zh + row * N_COLS + lane * 16;

  f16x8 h0 = *(const f16x8*)(p);
  f16x8 h1 = *(const f16x8*)(p + 8);
  float v[16];
  #pragma unroll
  for (int j = 0; j < 8; ++j) { v[j] = (float)h0[j]; v[8 + j] = (float)h1[j]; }

  float mx = v[0];
  #pragma unroll
  for (int j = 1; j < 16; ++j) mx = fmaxf(mx, v[j]);
  #pragma unroll
  for (int m = 1; m <= 32; m <<= 1) mx = fmaxf(mx, __shfl_xor(mx, m, 64));

  float lo = mx - 1.0f, hi = mx;
  for (int it = 0; it < 12; ++it) {
    float tau = 0.5f * (lo + hi);
    float s = 0.f;
    #pragma unroll
    for (int j = 0; j < 16; ++j) s += fmaxf(v[j] - tau, 0.f);
    #pragma unroll
    for (int m = 1; m <= 32; m <<= 1) s += __shfl_xor(s, m, 64);
    if (s >= 1.f) lo = tau; else hi = tau;
  }
  float tau = lo;
  #pragma unroll
  for (int it = 0; it < 2; ++it) {
    float s = 0.f, k = 0.f;
    #pragma unroll
    for (int j = 0; j < 16; ++j) {
      bool g = v[j] > tau;
      s += g ? v[j] : 0.f;
      k += g ? 1.f : 0.f;
    }
    #pragma unroll
    for (int m = 1; m <= 32; m <<= 1) { s += __shfl_xor(s, m, 64); k += __shfl_xor(k, m, 64); }
    tau = (s - 1.f) / k;   // k >= 1 (row max stays in support)
  }

  float* o = outp + row * N_COLS + lane * 16;
  #pragma unroll
  for (int j = 0; j < 4; ++j) {
    float4 t;
    t.x = fmaxf(v[j * 4 + 0] - tau, 0.f);
    t.y = fmaxf(v[j * 4 + 1] - tau, 0.f);
    t.z = fmaxf(v[j * 4 + 2] - tau, 0.f);
    t.w = fmaxf(v[j * 4 + 3] - tau, 0.f);
    *(float4*)(o + j * 4) = t;
  }
}

// ---------------- sparsemax in place on f32 z (mid path) ----------------
__global__ __launch_bounds__(256) void sparsemax_rows(float* __restrict__ z)
{
  const int lane = threadIdx.x & 63, wid = threadIdx.x >> 6;
  const size_t row = (size_t)blockIdx.x * 4 + wid;
  float* p = z + row * N_COLS;
  float v[16];
  #pragma unroll
  for (int j = 0; j < 4; ++j) {
    float4 t = *(const float4*)(p + j * 256 + lane * 4);
    v[j * 4 + 0] = t.x; v[j * 4 + 1] = t.y; v[j * 4 + 2] = t.z; v[j * 4 + 3] = t.w;
  }
  float mx = v[0];
  #pragma unroll
  for (int j = 1; j < 16; ++j) mx = fmaxf(mx, v[j]);
  #pragma unroll
  for (int m = 1; m <= 32; m <<= 1) mx = fmaxf(mx, __shfl_xor(mx, m, 64));
  float lo = mx - 1.0f, hi = mx;
  for (int it = 0; it < 12; ++it) {
    float tau = 0.5f * (lo + hi);
    float s = 0.f;
    #pragma unroll
    for (int j = 0; j < 16; ++j) s += fmaxf(v[j] - tau, 0.f);
    #pragma unroll
    for (int m = 1; m <= 32; m <<= 1) s += __shfl_xor(s, m, 64);
    if (s >= 1.f) lo = tau; else hi = tau;
  }
  float tau = lo;
  #pragma unroll
  for (int it = 0; it < 2; ++it) {
    float s = 0.f, k = 0.f;
    #pragma unroll
    for (int j = 0; j < 16; ++j) {
      bool g = v[j] > tau;
      s += g ? v[j] : 0.f;
      k += g ? 1.f : 0.f;
    }
    #pragma unroll
    for (int m = 1; m <= 32; m <<= 1) { s += __shfl_xor(s, m, 64); k += __shfl_xor(k, m, 64); }
    tau = (s - 1.f) / k;
  }
  #pragma unroll
  for (int j = 0; j < 4; ++j) {
    float4 t;
    t.x = fmaxf(v[j * 4 + 0] - tau, 0.f);
    t.y = fmaxf(v[j * 4 + 1] - tau, 0.f);
    t.z = fmaxf(v[j * 4 + 2] - tau, 0.f);
    t.w = fmaxf(v[j * 4 + 3] - tau, 0.f);
    *(float4*)(p + j * 256 + lane * 4) = t;
  }
}

// ---------------- FALLBACK GEMM (tiny ws): A reg-staged fp32->f16, 128^2 dbuf ----------------
__global__ __launch_bounds__(256, 2) void gemm_f16(
    const float* __restrict__ A, const _Float16* __restrict__ Wt,
    const float* __restrict__ bias, const float* __restrict__ priors,
    float* __restrict__ out)
{
  __shared__ char smem[65536];
  const int tid = threadIdx.x;
  const int lane = tid & 63, wid = tid >> 6;
  const int wm = wid >> 1, wnn = wid & 1;
  int orig = blockIdx.x;
  int wgid = (orig & 7) * 512 + (orig >> 3);
  int mb = wgid >> 3, nb = wgid & 7;
  const int m0 = mb * 128, n0 = nb * 128;
  f32x4 acc[4][4];
  #pragma unroll
  for (int i = 0; i < 4; ++i)
    #pragma unroll
    for (int j = 0; j < 4; ++j) acc[i][j] = (f32x4){0.f, 0.f, 0.f, 0.f};
  float4 areg[8];
  auto loadA = [&](int kt) {
    #pragma unroll
    for (int j = 0; j < 8; ++j) {
      int f = j * 256 + tid;
      int ml = f >> 4, k4 = (f & 15) << 2;
      areg[j] = *(const float4*)(A + (size_t)(m0 + ml) * K_DIM + kt * 64 + k4);
    }
  };
  auto storeA = [&](int buf) {
    int base = buf * 16384;
    #pragma unroll
    for (int j = 0; j < 8; ++j) {
      int f = j * 256 + tid;
      int ml = f >> 4, k4 = (f & 15) << 2;
      int off = ml * 128 + ((k4 * 2) ^ ((ml & 7) << 4));
      union { _Float16 h[4]; uint2 u; } p;
      p.h[0] = (_Float16)areg[j].x; p.h[1] = (_Float16)areg[j].y;
      p.h[2] = (_Float16)areg[j].z; p.h[3] = (_Float16)areg[j].w;
      *(uint2*)(&smem[base + off]) = p.u;
    }
  };
  auto issueB = [&](int kt, int buf) {
    int base = 32768 + buf * 16384;
    #pragma unroll
    for (int t4 = 0; t4 < 4; ++t4) {
      int ch = t4 * 256 + tid;
      int nl = ch >> 3, c = ch & 7;
      const char* src = (const char*)Wt + ((size_t)(n0 + nl) * K_DIM + kt * 64) * 2
          + ((c * 16) ^ ((nl & 7) << 4));
      __builtin_amdgcn_global_load_lds(
          (const __attribute__((address_space(1))) unsigned int*)src,
          (__attribute__((address_space(3))) unsigned int*)(&smem[base + ch * 16]),
          16, 0, 0);
    }
  };
  loadA(0); issueB(0, 0); storeA(0);
  __syncthreads();
  for (int kt = 0; kt < 16; ++kt) {
    int curb = kt & 1, nxt = curb ^ 1;
    if (kt < 15) { loadA(kt + 1); issueB(kt + 1, nxt); }
    int ab = curb * 16384, bb = 32768 + curb * 16384;
    #pragma unroll
    for (int kc = 0; kc < 2; ++kc) {
      int k2 = (kc * 32 + ((lane >> 4) * 8)) * 2;
      f16x8 af[4], bfr[4];
      #pragma unroll
      for (int fm = 0; fm < 4; ++fm) {
        int rl2 = wm * 64 + fm * 16 + (lane & 15);
        af[fm] = *(const f16x8*)(&smem[ab + rl2 * 128 + (k2 ^ ((rl2 & 7) << 4))]);
      }
      #pragma unroll
      for (int fn = 0; fn < 4; ++fn) {
        int nl = wnn * 64 + fn * 16 + (lane & 15);
        bfr[fn] = *(const f16x8*)(&smem[bb + nl * 128 + (k2 ^ ((nl & 7) << 4))]);
      }
      #pragma unroll
      for (int fm = 0; fm < 4; ++fm)
        #pragma unroll
        for (int fn = 0; fn < 4; ++fn)
          acc[fm][fn] = __builtin_amdgcn_mfma_f32_16x16x32_f16(af[fm], bfr[fn], acc[fm][fn], 0, 0, 0);
    }
    if (kt < 15) storeA(nxt);
    __syncthreads();
  }
  #pragma unroll
  for (int fn = 0; fn < 4; ++fn) {
    int col = n0 + wnn * 64 + fn * 16 + (lane & 15);
    float bvv = bias[col];
    #pragma unroll
    for (int fm = 0; fm < 4; ++fm) {
      int row0 = m0 + wm * 64 + fm * 16 + ((lane >> 4) << 2);
      #pragma unroll
      for (int r = 0; r < 4; ++r) {
        size_t idx = (size_t)(row0 + r) * N_COLS + col;
        out[idx] = (acc[fm][fn][r] + bvv) * priors[idx];
      }
    }
  }
}

// ---------------- launch ----------------
extern "C" void kernel_launch(void* const* d_in, const int* in_sizes, int n_in,
                              void* d_out, int out_size, void* d_ws, size_t ws_size,
                              hipStream_t stream) {
  const float* inputs = (const float*)d_in[0];
  const float* priors = (const float*)d_in[1];
  const float* W      = (const float*)d_in[2];
  const float* gamma  = (const float*)d_in[3];
  const float* beta   = (const float*)d_in[4];
  const float* mean   = (const float*)d_in[5];
  const float* var    = (const float*)d_in[6];
  float* out = (float*)d_out;

  char* ws = (char*)d_ws;
  float* bias  = (float*)ws;                 // 4 KB
  float* scale = (float*)(ws + 4096);        // 4 KB
  _Float16* Wt = (_Float16*)(ws + 8192);     // 2 MB, [N][K] transposed+scaled
  const size_t ZH_OFF = 8192 + (size_t)N_COLS * K_DIM * 2;          // 2105344
  _Float16* zh = (_Float16*)(ws + ZH_OFF);   // 134 MB, [M][N] f16 z
  const size_t needWt = ZH_OFF;
  const size_t needZh = ZH_OFF + (size_t)M_ROWS * N_COLS * 2;

  prep_scale_bias<<<4, 256, 0, stream>>>(gamma, beta, mean, var, bias, scale);
  prep_wt<<<dim3(16, 16), 256, 0, stream>>>(W, scale, Wt);

  if (ws_size >= needZh) {
    gemm_256c<1><<<1024, 512, 0, stream>>>(inputs, Wt, bias, priors, zh);
    sparsemax_rows_h<<<16384, 256, 0, stream>>>(zh, out);
  } else if (ws_size >= needWt) {
    gemm_256c<0><<<1024, 512, 0, stream>>>(inputs, Wt, bias, priors, out);
    sparsemax_rows<<<16384, 256, 0, stream>>>(out);
  } else {
    gemm_f16<<<4096, 256, 0, stream>>>(inputs, Wt, bias, priors, out);
    sparsemax_rows<<<16384, 256, 0, stream>>>(out);
  }
}